// Round 17
// baseline (205.013 us; speedup 1.0000x reference)
//
#include <hip/hip_runtime.h>
#include <hip/hip_cooperative_groups.h>

namespace cg = cooperative_groups;

typedef unsigned short u16;
typedef __bf16 bfloat;
typedef bfloat bf16x8 __attribute__((ext_vector_type(8)));
typedef float f32x4 __attribute__((ext_vector_type(4)));
typedef u16 v8u16 __attribute__((ext_vector_type(8)));

#define B_ 32
#define L_ 200
#define D_ 512
#define H_ 8
#define HD_ 64
#define M_ (B_*L_)

__device__ __forceinline__ float bf2f(u16 u) {
  union { float f; unsigned int i; } v; v.i = ((unsigned int)u) << 16; return v.f;
}
__device__ __forceinline__ u16 f2bf(float f) {
  union { float f; unsigned int i; } v; v.f = f;
  unsigned int i = v.i;
  return (u16)((i + 0x7FFFu + ((i >> 16) & 1u)) >> 16);
}
__device__ __forceinline__ bf16x8 as_bf(v8u16 v) { return __builtin_bit_cast(bf16x8, v); }

__device__ __forceinline__ void gload16(const void* g, void* l) {
  __builtin_amdgcn_global_load_lds(
      (const __attribute__((address_space(1))) void*)g,
      (__attribute__((address_space(3))) void*)l,
      16, 0, 0);
}

struct TPtrs { const float* s[12]; };

// =================== shared item bodies (used by BOTH paths) ===================

__device__ void prep_item(const float* __restrict__ x, const unsigned char* __restrict__ mask,
                          u16* __restrict__ qb, TPtrs tp, u16* __restrict__ Wt,
                          const float* __restrict__ ln1g, const float* __restrict__ ln1b,
                          u16* __restrict__ Qn, int bid, int t, float* T)
{
  if (bid < 1600) {
    size_t i = (size_t)bid * 256 + t;
    size_t base = i * 8;
    int tok = (int)(base >> 9);
    float valid = mask[tok] ? 0.f : 1.f;
    float4 v0 = *(const float4*)(x + base);
    float4 v1 = *(const float4*)(x + base + 4);
    v8u16 ob;
    ob[0]=f2bf(v0.x*valid); ob[1]=f2bf(v0.y*valid); ob[2]=f2bf(v0.z*valid); ob[3]=f2bf(v0.w*valid);
    ob[4]=f2bf(v1.x*valid); ob[5]=f2bf(v1.y*valid); ob[6]=f2bf(v1.z*valid); ob[7]=f2bf(v1.w*valid);
    *(v8u16*)(qb + base) = ob;
    int lane = t & 63;
    float xs[8];
    #pragma unroll
    for (int j = 0; j < 8; j++) xs[j] = bf2f(ob[j]);
    float s = 0.f, q = 0.f;
    #pragma unroll
    for (int j = 0; j < 8; j++) { s += xs[j]; q += xs[j] * xs[j]; }
    #pragma unroll
    for (int off = 1; off < 64; off <<= 1) { s += __shfl_xor(s, off); q += __shfl_xor(q, off); }
    float mean = s * (1.f / 512.f);
    float var  = fmaxf(q * (1.f / 512.f) - mean * mean, 0.f);
    float rstd = rsqrtf(var + 1e-8f);
    float4 g0 = *(const float4*)(ln1g + lane * 8);
    float4 g1 = *(const float4*)(ln1g + lane * 8 + 4);
    float4 b0 = *(const float4*)(ln1b + lane * 8);
    float4 b1 = *(const float4*)(ln1b + lane * 8 + 4);
    float gv[8] = {g0.x,g0.y,g0.z,g0.w,g1.x,g1.y,g1.z,g1.w};
    float bv[8] = {b0.x,b0.y,b0.z,b0.w,b1.x,b1.y,b1.z,b1.w};
    v8u16 qn;
    #pragma unroll
    for (int j = 0; j < 8; j++) qn[j] = f2bf((xs[j] - mean) * rstd * gv[j] + bv[j]);
    *(v8u16*)(Qn + base) = qn;
  } else {
    int wb   = bid - 1600;
    int mat  = wb >> 6;
    int tile = wb & 63;
    int tr = tile >> 3, tc = tile & 7;
    const float* src = tp.s[mat];
    #pragma unroll
    for (int i = 0; i < 4; i++) {
      int idx = t + i * 256;
      int row = idx >> 4, c4 = idx & 15;
      float4 v = *(const float4*)(src + (size_t)(tr * 64 + row) * 512 + tc * 64 + c4 * 4);
      T[row * 65 + c4 * 4 + 0] = v.x; T[row * 65 + c4 * 4 + 1] = v.y;
      T[row * 65 + c4 * 4 + 2] = v.z; T[row * 65 + c4 * 4 + 3] = v.w;
    }
    __syncthreads();
    u16* d = Wt + (size_t)mat * 262144;
    #pragma unroll
    for (int i = 0; i < 2; i++) {
      int idx = t + i * 256;
      int row = idx >> 3, c8 = idx & 7;
      v8u16 v;
      #pragma unroll
      for (int j = 0; j < 8; j++) v[j] = f2bf(T[(c8 * 8 + j) * 65 + row]);
      *(v8u16*)(d + (size_t)(tc * 64 + row) * 512 + tr * 64 + c8 * 8) = v;
    }
  }
}

template<bool OUTF32>
__device__ void ln_item(int bid, int t, const u16* __restrict__ in,
                        const float* __restrict__ g, const float* __restrict__ b,
                        u16* __restrict__ outb, float* __restrict__ outf) {
  int row  = bid * 4 + (t >> 6);
  int lane = t & 63;
  size_t base = (size_t)row * 512 + lane * 8;
  v8u16 xv = *(const v8u16*)(in + base);
  float xs[8];
  #pragma unroll
  for (int j = 0; j < 8; j++) xs[j] = bf2f(xv[j]);
  float s = 0.f, q = 0.f;
  #pragma unroll
  for (int j = 0; j < 8; j++) { s += xs[j]; q += xs[j] * xs[j]; }
  #pragma unroll
  for (int off = 1; off < 64; off <<= 1) { s += __shfl_xor(s, off); q += __shfl_xor(q, off); }
  float mean = s * (1.f / 512.f);
  float var  = fmaxf(q * (1.f / 512.f) - mean * mean, 0.f);
  float rstd = rsqrtf(var + 1e-8f);
  float4 g0 = *(const float4*)(g + lane * 8);
  float4 g1 = *(const float4*)(g + lane * 8 + 4);
  float4 b0 = *(const float4*)(b + lane * 8);
  float4 b1 = *(const float4*)(b + lane * 8 + 4);
  float gv[8] = {g0.x,g0.y,g0.z,g0.w,g1.x,g1.y,g1.z,g1.w};
  float bv[8] = {b0.x,b0.y,b0.z,b0.w,b1.x,b1.y,b1.z,b1.w};
  if (OUTF32) {
    float of[8];
    #pragma unroll
    for (int j = 0; j < 8; j++) of[j] = (xs[j] - mean) * rstd * gv[j] + bv[j];
    *(float4*)(outf + base)     = make_float4(of[0], of[1], of[2], of[3]);
    *(float4*)(outf + base + 4) = make_float4(of[4], of[5], of[6], of[7]);
  } else {
    v8u16 ob;
    #pragma unroll
    for (int j = 0; j < 8; j++) ob[j] = f2bf((xs[j] - mean) * rstd * gv[j] + bv[j]);
    *(v8u16*)(outb + base) = ob;
  }
}

__device__ __forceinline__ void stage128(const u16* __restrict__ src, int r0, int kk,
                                         u16* dstLds, int wid, int lane) {
  int g = lane & 15;
  #pragma unroll
  for (int j = 0; j < 4; j++) {
    int row = j * 16 + wid * 4 + (lane >> 4);
    int gsrc = (g & 8) | ((g & 7) ^ (row & 7));
    gload16(src + (size_t)(r0 + row) * 512 + kk + gsrc * 8,
            (char*)dstLds + (j * 16 + wid * 4) * 256);
  }
}

__device__ __forceinline__ void gemm_core128(
    const u16* __restrict__ A, const u16* __restrict__ Wt,
    int m0, int n0, u16* As, u16* Bs, f32x4 (&acc)[2][2], int tid)
{
  int wid = tid >> 6, lane = tid & 63;
  int wr = wid >> 1, wc = wid & 1;
  int l15 = lane & 15, hi = lane >> 4;
  for (int s = 0; s < 4; s++) {
    int kk = s * 128;
    stage128(A,  m0, kk, As, wid, lane);
    stage128(Wt, n0, kk, Bs, wid, lane);
    __syncthreads();
    #pragma unroll
    for (int ksub = 0; ksub < 4; ksub++) {
      int G = ksub * 4 + hi;
      bf16x8 af[2], bfr[2];
      #pragma unroll
      for (int mi = 0; mi < 2; mi++) {
        int ra = wr * 32 + mi * 16 + l15;
        int lg = (G & 8) | ((G & 7) ^ (ra & 7));
        af[mi] = *(const bf16x8*)(As + ra * 128 + lg * 8);
      }
      #pragma unroll
      for (int ni = 0; ni < 2; ni++) {
        int rn = wc * 32 + ni * 16 + l15;
        int lg = (G & 8) | ((G & 7) ^ (rn & 7));
        bfr[ni] = *(const bf16x8*)(Bs + rn * 128 + lg * 8);
      }
      #pragma unroll
      for (int mi = 0; mi < 2; mi++)
        #pragma unroll
        for (int ni = 0; ni < 2; ni++)
          acc[mi][ni] = __builtin_amdgcn_mfma_f32_16x16x32_bf16(af[mi], bfr[ni], acc[mi][ni], 0, 0, 0);
    }
    __syncthreads();
  }
}

template<bool RELU, bool HAS_RES, bool MASK>
__device__ void gemm_item(const u16* __restrict__ A, const u16* __restrict__ Wt,
                          const float* __restrict__ bias, const u16* __restrict__ res,
                          const unsigned char* __restrict__ mask, u16* __restrict__ outb,
                          int bid, int tid, u16* sh)
{
  u16* As = sh;
  u16* Bs = sh + 16384;
  int tile = (bid & 7) * 50 + (bid >> 3);
  int m0 = (tile >> 3) * 128, n0 = (tile & 7) * 64;
  int wid = tid >> 6, lane = tid & 63;
  int l15 = lane & 15, hi = lane >> 4;
  f32x4 acc[2][4] = {};
  for (int s = 0; s < 4; s++) {
    int kk = s * 128;
    stage128(A,  m0,      kk, As,            wid, lane);
    stage128(A,  m0 + 64, kk, As + 64 * 128, wid, lane);
    stage128(Wt, n0,      kk, Bs,            wid, lane);
    __syncthreads();
    #pragma unroll
    for (int ksub = 0; ksub < 4; ksub++) {
      int G = ksub * 4 + hi;
      bf16x8 af[2], bfr[4];
      #pragma unroll
      for (int mi = 0; mi < 2; mi++) {
        int ra = wid * 32 + mi * 16 + l15;
        int lg = (G & 8) | ((G & 7) ^ (ra & 7));
        af[mi] = *(const bf16x8*)(As + ra * 128 + lg * 8);
      }
      #pragma unroll
      for (int ni = 0; ni < 4; ni++) {
        int rn = ni * 16 + l15;
        int lg = (G & 8) | ((G & 7) ^ (rn & 7));
        bfr[ni] = *(const bf16x8*)(Bs + rn * 128 + lg * 8);
      }
      #pragma unroll
      for (int mi = 0; mi < 2; mi++)
        #pragma unroll
        for (int ni = 0; ni < 4; ni++)
          acc[mi][ni] = __builtin_amdgcn_mfma_f32_16x16x32_bf16(af[mi], bfr[ni], acc[mi][ni], 0, 0, 0);
    }
    __syncthreads();
  }
  #pragma unroll
  for (int ni = 0; ni < 4; ni++) {
    int gc = n0 + ni * 16 + l15;
    float bvv = bias[gc];
    #pragma unroll
    for (int mi = 0; mi < 2; mi++) {
      int grb = m0 + wid * 32 + mi * 16 + hi * 4;
      #pragma unroll
      for (int r = 0; r < 4; r++) {
        int gr = grb + r;
        float v = acc[mi][ni][r] + bvv;
        if (HAS_RES) v += bf2f(res[(size_t)gr * 512 + gc]);
        if (RELU) v = fmaxf(v, 0.f);
        if (MASK) v = mask[gr] ? 0.f : v;
        outb[(size_t)gr * 512 + gc] = f2bf(v);
      }
    }
  }
}

__device__ void qkv_item(const u16* __restrict__ Aq, const u16* __restrict__ Akv,
                         const u16* __restrict__ Wtq, const u16* __restrict__ Wtk,
                         const u16* __restrict__ Wtv,
                         const float* __restrict__ bq, const float* __restrict__ bk,
                         const float* __restrict__ bv,
                         u16* __restrict__ outq, u16* __restrict__ outk, u16* __restrict__ outvt,
                         int bid, int tid, u16* sh)
{
  int tile = (bid & 7) * 200 + (bid >> 3);
  int wid = tid >> 6, lane = tid & 63;
  int wr = wid >> 1, wc = wid & 1;
  int l15 = lane & 15, hi = lane >> 4;
  u16* As = sh;
  u16* B0 = sh + 8192;
  u16* B1 = sh + 16384;

  if (tile < 800) {
    int m0 = (tile >> 3) * 64, n0 = (tile & 7) * 64;
    f32x4 acc[2][2] = {};
    gemm_core128(Aq, Wtq, m0, n0, As, B0, acc, tid);
    #pragma unroll
    for (int ni = 0; ni < 2; ni++) {
      int gc = n0 + wc * 32 + ni * 16 + l15;
      float bvv = bq[gc];
      #pragma unroll
      for (int mi = 0; mi < 2; mi++) {
        int grb = m0 + wr * 32 + mi * 16 + hi * 4;
        #pragma unroll
        for (int r = 0; r < 4; r++)
          outq[(size_t)(grb + r) * 512 + gc] = f2bf(acc[mi][ni][r] + bvv);
      }
    }
  } else {
    int t2 = tile - 800;
    int m0 = (t2 >> 3) * 64, n0 = (t2 & 7) * 64;
    f32x4 ak[2][2] = {}, av[2][2] = {};
    for (int s = 0; s < 4; s++) {
      int kk = s * 128;
      stage128(Akv, m0, kk, As, wid, lane);
      stage128(Wtk, n0, kk, B0, wid, lane);
      stage128(Wtv, n0, kk, B1, wid, lane);
      __syncthreads();
      #pragma unroll
      for (int ksub = 0; ksub < 4; ksub++) {
        int G = ksub * 4 + hi;
        bf16x8 af[2], bkf[2], bvf[2];
        #pragma unroll
        for (int mi = 0; mi < 2; mi++) {
          int ra = wr * 32 + mi * 16 + l15;
          int lg = (G & 8) | ((G & 7) ^ (ra & 7));
          af[mi] = *(const bf16x8*)(As + ra * 128 + lg * 8);
        }
        #pragma unroll
        for (int ni = 0; ni < 2; ni++) {
          int rn = wc * 32 + ni * 16 + l15;
          int lg = (G & 8) | ((G & 7) ^ (rn & 7));
          bkf[ni] = *(const bf16x8*)(B0 + rn * 128 + lg * 8);
          bvf[ni] = *(const bf16x8*)(B1 + rn * 128 + lg * 8);
        }
        #pragma unroll
        for (int mi = 0; mi < 2; mi++)
          #pragma unroll
          for (int ni = 0; ni < 2; ni++) {
            ak[mi][ni] = __builtin_amdgcn_mfma_f32_16x16x32_bf16(af[mi], bkf[ni], ak[mi][ni], 0, 0, 0);
            av[mi][ni] = __builtin_amdgcn_mfma_f32_16x16x32_bf16(af[mi], bvf[ni], av[mi][ni], 0, 0, 0);
          }
      }
      __syncthreads();
    }
    #pragma unroll
    for (int ni = 0; ni < 2; ni++) {
      int gc = n0 + wc * 32 + ni * 16 + l15;
      float bkv = bk[gc], bvv = bv[gc];
      int h = gc >> 6, hd = gc & 63;
      #pragma unroll
      for (int mi = 0; mi < 2; mi++) {
        int grb = m0 + wr * 32 + mi * 16 + hi * 4;
        #pragma unroll
        for (int r = 0; r < 4; r++) {
          int gr = grb + r;
          outk[(size_t)gr * 512 + gc] = f2bf(ak[mi][ni][r] + bkv);
          int b = gr / 200, l = gr - b * 200;
          outvt[((size_t)(b * 8 + h) * 64 + hd) * 224 + l] = f2bf(av[mi][ni][r] + bvv);
        }
      }
    }
  }
}

__device__ void attn_item(const u16* __restrict__ Qh, const u16* __restrict__ Kh,
                          const u16* __restrict__ Vt, u16* __restrict__ ctx,
                          int bid, int lane, u16* Pw)
{
  int xcd = bid & 7, j = bid >> 3;
  int bh_hi = j / 7, s = j - bh_hi * 7;
  int bh = bh_hi * 8 + xcd;
  int b = bh >> 3, h = bh & 7;
  int l15 = lane & 15, hi = lane >> 4;

  const u16* Kg = Kh + (size_t)(b * L_) * D_ + h * HD_;
  const u16* Vg = Vt + (size_t)bh * 64 * 224;

  int tA = (s < 6) ? (12 - s) : 6;
  int tB = (s < 6) ? s : -1;

  for (int jj = 0; jj < 2; jj++) {
    int t = jj ? tB : tA;
    if (t < 0) break;
    int q0 = t * 16;
    int qrow = q0 + l15; if (qrow > L_ - 1) qrow = L_ - 1;
    const u16* Qg = Qh + (size_t)(b * L_ + qrow) * D_ + h * HD_ + hi * 8;
    bf16x8 aq0 = as_bf(*(const v8u16*)(Qg));
    bf16x8 aq1 = as_bf(*(const v8u16*)(Qg + 32));

    f32x4 sv[13];
    float m0[4];
    #pragma unroll
    for (int r = 0; r < 4; r++) m0[r] = -3.0e38f;

    #pragma unroll
    for (int kt = 0; kt < 13; kt++) {
      if (kt <= t) {
        const u16* kp = Kg + (size_t)(kt * 16 + l15) * D_ + hi * 8;
        bf16x8 bk0 = as_bf(*(const v8u16*)(kp));
        bf16x8 bk1 = as_bf(*(const v8u16*)(kp + 32));
        f32x4 acq = {0.f, 0.f, 0.f, 0.f};
        acq = __builtin_amdgcn_mfma_f32_16x16x32_bf16(aq0, bk0, acq, 0, 0, 0);
        acq = __builtin_amdgcn_mfma_f32_16x16x32_bf16(aq1, bk1, acq, 0, 0, 0);
        #pragma unroll
        for (int r = 0; r < 4; r++) {
          int qr = q0 + hi * 4 + r;
          int kc = kt * 16 + l15;
          float val = (kc <= qr && qr < L_) ? acq[r] * 0.125f : -3.0e38f;
          sv[kt][r] = val;
          m0[r] = fmaxf(m0[r], val);
        }
      }
    }
    #pragma unroll
    for (int r = 0; r < 4; r++) {
      #pragma unroll
      for (int off = 1; off < 16; off <<= 1)
        m0[r] = fmaxf(m0[r], __shfl_xor(m0[r], off));
      if (m0[r] < -1e37f) m0[r] = 0.f;
    }
    float sum[4] = {0.f, 0.f, 0.f, 0.f};
    #pragma unroll
    for (int kt = 0; kt < 13; kt++) {
      if (kt <= t) {
        #pragma unroll
        for (int r = 0; r < 4; r++) {
          float p = __expf(sv[kt][r] - m0[r]);
          sv[kt][r] = p;
          sum[r] += p;
        }
      }
    }
    #pragma unroll
    for (int r = 0; r < 4; r++) {
      #pragma unroll
      for (int off = 1; off < 16; off <<= 1) sum[r] += __shfl_xor(sum[r], off);
    }
    float inv[4];
    #pragma unroll
    for (int r = 0; r < 4; r++) inv[r] = sum[r] > 0.f ? 1.f / sum[r] : 0.f;

    int ksmax = (t + 2) >> 1;
    f32x4 acc[4] = {};
    #pragma unroll
    for (int ks = 0; ks < 7; ks++) {
      if (ks < ksmax) {
        u16* Ps = Pw + (ks & 1) * 512;
        #pragma unroll
        for (int half = 0; half < 2; half++) {
          int kt = ks * 2 + half;
          #pragma unroll
          for (int r = 0; r < 4; r++) {
            float pv = (kt <= t) ? sv[kt][r] : 0.f;
            Ps[(hi * 4 + r) * 32 + half * 16 + l15] = f2bf(pv);
          }
        }
        bf16x8 ap = as_bf(*(const v8u16*)(Ps + l15 * 32 + hi * 8));
        #pragma unroll
        for (int nt = 0; nt < 4; nt++) {
          bf16x8 bvv = as_bf(*(const v8u16*)(Vg + (nt * 16 + l15) * 224 + ks * 32 + hi * 8));
          acc[nt] = __builtin_amdgcn_mfma_f32_16x16x32_bf16(ap, bvv, acc[nt], 0, 0, 0);
        }
      }
    }
    #pragma unroll
    for (int nt = 0; nt < 4; nt++) {
      #pragma unroll
      for (int r = 0; r < 4; r++) {
        int qr = q0 + hi * 4 + r;
        if (qr < L_) ctx[(size_t)(b * L_ + qr) * D_ + h * HD_ + nt * 16 + l15] = f2bf(acc[nt][r] * inv[r]);
      }
    }
  }
}

// =================== standalone kernels (R15-proven fallback path) ===================

__global__ __launch_bounds__(256) void prep_kernel(
    const float* __restrict__ x, const unsigned char* __restrict__ mask,
    u16* __restrict__ qb, TPtrs tp, u16* __restrict__ Wt,
    const float* __restrict__ ln1g, const float* __restrict__ ln1b, u16* __restrict__ Qn)
{
  __shared__ float T[64 * 65];
  prep_item(x, mask, qb, tp, Wt, ln1g, ln1b, Qn, blockIdx.x, threadIdx.x, T);
}

template<bool OUTF32>
__global__ __launch_bounds__(256) void ln_kernel(
    const u16* __restrict__ in, const float* __restrict__ g, const float* __restrict__ b,
    u16* __restrict__ outb, float* __restrict__ outf)
{
  ln_item<OUTF32>(blockIdx.x, threadIdx.x, in, g, b, outb, outf);
}

template<bool RELU, bool HAS_RES, bool MASK>
__global__ __launch_bounds__(256) void gemm_one(
    const u16* __restrict__ A, const u16* __restrict__ Wt, const float* __restrict__ bias,
    const u16* __restrict__ res, const unsigned char* __restrict__ mask,
    u16* __restrict__ outb)
{
  __shared__ u16 sh[24576];
  gemm_item<RELU, HAS_RES, MASK>(A, Wt, bias, res, mask, outb, blockIdx.x, threadIdx.x, sh);
}

__global__ __launch_bounds__(256) void gemm_qkv(
    const u16* __restrict__ Aq, const u16* __restrict__ Akv,
    const u16* __restrict__ Wtq, const u16* __restrict__ Wtk, const u16* __restrict__ Wtv,
    const float* __restrict__ bq, const float* __restrict__ bk, const float* __restrict__ bv,
    u16* __restrict__ outq, u16* __restrict__ outk, u16* __restrict__ outvt)
{
  __shared__ u16 sh[24576];
  qkv_item(Aq, Akv, Wtq, Wtk, Wtv, bq, bk, bv, outq, outk, outvt, blockIdx.x, threadIdx.x, sh);
}

__global__ __launch_bounds__(64) void attn_kernel(
    const u16* __restrict__ Qh, const u16* __restrict__ Kh,
    const u16* __restrict__ Vt, u16* __restrict__ ctx)
{
  __shared__ u16 Pw[1024];
  attn_item(Qh, Kh, Vt, ctx, blockIdx.x, threadIdx.x, Pw);
}

// =================== cooperative mega-kernel path ===================

struct Args {
  const float* x; const unsigned char* mask;
  const float* ln1g; const float* ln1b;
  const float* bq; const float* bk; const float* bv; const float* bo;
  const float* ln2g; const float* ln2b;
  const float* b1; const float* b2;
  const float* lnfg; const float* lnfb;
  TPtrs tp;
  u16 *Wt, *qb, *Qn, *qh, *kh, *vh, *Vtb;
  float* out;
};

__global__ __launch_bounds__(256, 2) void mega_kernel(Args a)
{
  cg::grid_group grid = cg::this_grid();
  __shared__ u16 sh[24576];   // 48 KB, reused per stage
  int wg = blockIdx.x;
  int tid = threadIdx.x;
  int nwg = gridDim.x;

  for (int it = wg; it < 2368; it += nwg) {
    prep_item(a.x, a.mask, a.qb, a.tp, a.Wt, a.ln1g, a.ln1b, a.Qn, it, tid, (float*)sh);
    __syncthreads();
  }
  grid.sync();

  for (int layer = 0; layer < 2; layer++) {
    const u16* Wtq = a.Wt + (size_t)(0  + layer) * 262144;
    const u16* Wtk = a.Wt + (size_t)(2  + layer) * 262144;
    const u16* Wtv = a.Wt + (size_t)(4  + layer) * 262144;
    const u16* Wto = a.Wt + (size_t)(6  + layer) * 262144;
    const u16* Wt1 = a.Wt + (size_t)(8  + layer) * 262144;
    const u16* Wt2 = a.Wt + (size_t)(10 + layer) * 262144;

    if (layer) {
      for (int it = wg; it < 1600; it += nwg)
        ln_item<false>(it, tid, a.qb, a.ln1g + 512, a.ln1b + 512, a.Qn, nullptr);
      grid.sync();
    }
    for (int it = wg; it < 1600; it += nwg) {
      qkv_item(a.Qn, a.qb, Wtq, Wtk, Wtv, a.bq + layer * 512, a.bk + layer * 512,
               a.bv + layer * 512, a.qh, a.kh, a.Vtb, it, tid, sh);
      __syncthreads();
    }
    grid.sync();
    {
      int wid = tid >> 6, lane = tid & 63;
      u16* Pw = sh + wid * 1024;
      for (int it = wg * 4 + wid; it < 1792; it += nwg * 4)
        attn_item(a.qh, a.kh, a.Vtb, a.vh, it, lane, Pw);
    }
    __syncthreads();
    grid.sync();
    for (int it = wg; it < 400; it += nwg) {
      gemm_item<false,true,false>(a.vh, Wto, a.bo + layer * 512, a.Qn, nullptr, a.qb, it, tid, sh);
      __syncthreads();
    }
    grid.sync();
    for (int it = wg; it < 1600; it += nwg)
      ln_item<false>(it, tid, a.qb, a.ln2g + layer * 512, a.ln2b + layer * 512, a.Qn, nullptr);
    grid.sync();
    for (int it = wg; it < 400; it += nwg) {
      gemm_item<true,false,false>(a.Qn, Wt1, a.b1 + layer * 512, nullptr, nullptr, a.qh, it, tid, sh);
      __syncthreads();
    }
    grid.sync();
    for (int it = wg; it < 400; it += nwg) {
      gemm_item<false,true,true>(a.qh, Wt2, a.b2 + layer * 512, a.Qn, a.mask, a.qb, it, tid, sh);
      __syncthreads();
    }
    grid.sync();
  }
  for (int it = wg; it < 1600; it += nwg)
    ln_item<true>(it, tid, a.qb, a.lnfg, a.lnfb, nullptr, a.out);
}

// =================== host ===================

extern "C" void kernel_launch(void* const* d_in, const int* in_sizes, int n_in,
                              void* d_out, int out_size, void* d_ws, size_t ws_size,
                              hipStream_t stream)
{
  (void)in_sizes; (void)n_in; (void)out_size; (void)ws_size;
  Args a;
  a.x    = (const float*)d_in[0];
  a.mask = (const unsigned char*)d_in[1];
  a.ln1g = (const float*)d_in[2];
  a.ln1b = (const float*)d_in[3];
  const float* Wq = (const float*)d_in[4];  a.bq = (const float*)d_in[5];
  const float* Wk = (const float*)d_in[6];  a.bk = (const float*)d_in[7];
  const float* Wv = (const float*)d_in[8];  a.bv = (const float*)d_in[9];
  const float* Wo = (const float*)d_in[10]; a.bo = (const float*)d_in[11];
  a.ln2g = (const float*)d_in[12];
  a.ln2b = (const float*)d_in[13];
  const float* W1 = (const float*)d_in[14]; a.b1 = (const float*)d_in[15];
  const float* W2 = (const float*)d_in[16]; a.b2 = (const float*)d_in[17];
  a.lnfg = (const float*)d_in[18];
  a.lnfb = (const float*)d_in[19];

  a.tp.s[0] = Wq; a.tp.s[1] = Wq + 262144;
  a.tp.s[2] = Wk; a.tp.s[3] = Wk + 262144;
  a.tp.s[4] = Wv; a.tp.s[5] = Wv + 262144;
  a.tp.s[6] = Wo; a.tp.s[7] = Wo + 262144;
  a.tp.s[8] = W1; a.tp.s[9] = W1 + 262144;
  a.tp.s[10] = W2; a.tp.s[11] = W2 + 262144;

  char* ws = (char*)d_ws;
  a.Wt  = (u16*)(ws);
  a.qb  = (u16*)(ws +  6291456);
  a.Qn  = (u16*)(ws + 12845056);
  a.qh  = (u16*)(ws + 19398656);
  a.kh  = (u16*)(ws + 25952256);
  a.vh  = (u16*)(ws + 32505856);
  a.Vtb = (u16*)(ws + 39059456);
  a.out = (float*)d_out;

  // ---- try cooperative mega-kernel, sized by measured occupancy ----
  bool coop_ok = false;
  int nb = 0;
  if (hipOccupancyMaxActiveBlocksPerMultiprocessor(&nb, mega_kernel, 256, 0) == hipSuccess && nb > 0) {
    int dev = 0, ncu = 0;
    hipGetDevice(&dev);
    hipDeviceGetAttribute(&ncu, hipDeviceAttributeMultiprocessorCount, dev);
    if (ncu > 0) {
      long maxg = (long)nb * ncu;
      int grid = (int)(maxg < 512 ? maxg : 512);
      if (grid >= 64) {
        void* params[] = { (void*)&a };
        if (hipLaunchCooperativeKernel((const void*)mega_kernel, dim3(grid), dim3(256),
                                       params, 0, stream) == hipSuccess)
          coop_ok = true;
      }
    }
  }
  if (coop_ok) return;

  // ---- fallback: R15-proven 15-launch path (bit-identical math) ----
  prep_kernel<<<dim3(2368), dim3(256), 0, stream>>>(a.x, a.mask, a.qb, a.tp, a.Wt, a.ln1g, a.ln1b, a.Qn);
  for (int i = 0; i < 2; i++) {
    const u16* Wtq = a.Wt + (size_t)(0 + i) * 262144;
    const u16* Wtk = a.Wt + (size_t)(2 + i) * 262144;
    const u16* Wtv = a.Wt + (size_t)(4 + i) * 262144;
    const u16* Wto = a.Wt + (size_t)(6 + i) * 262144;
    const u16* Wt1 = a.Wt + (size_t)(8 + i) * 262144;
    const u16* Wt2 = a.Wt + (size_t)(10 + i) * 262144;

    if (i) ln_kernel<false><<<dim3(1600), dim3(256), 0, stream>>>(a.qb, a.ln1g + 512, a.ln1b + 512, a.Qn, nullptr);
    gemm_qkv<<<dim3(1600), dim3(256), 0, stream>>>(a.Qn, a.qb, Wtq, Wtk, Wtv,
                                                   a.bq + i * 512, a.bk + i * 512, a.bv + i * 512,
                                                   a.qh, a.kh, a.Vtb);
    attn_kernel<<<dim3(1792), dim3(64), 0, stream>>>(a.qh, a.kh, a.Vtb, a.vh);
    gemm_one<false,true,false><<<dim3(400), dim3(256), 0, stream>>>(a.vh, Wto, a.bo + i * 512, a.Qn, nullptr, a.qb);
    ln_kernel<false><<<dim3(1600), dim3(256), 0, stream>>>(a.qb, a.ln2g + i * 512, a.ln2b + i * 512, a.Qn, nullptr);
    gemm_one<true,false,false><<<dim3(400), dim3(256), 0, stream>>>(a.Qn, Wt1, a.b1 + i * 512, nullptr, nullptr, a.qh);
    gemm_one<false,true,true><<<dim3(400), dim3(256), 0, stream>>>(a.qh, Wt2, a.b2 + i * 512, a.Qn, a.mask, a.qb);
  }
  ln_kernel<true><<<dim3(1600), dim3(256), 0, stream>>>(a.qb, a.lnfg, a.lnfb, nullptr, (float*)d_out);
}

// Round 18
// 170.677 us; speedup vs baseline: 1.2012x; 1.2012x over previous
//
#include <hip/hip_runtime.h>

typedef unsigned short u16;
typedef __bf16 bfloat;
typedef bfloat bf16x8 __attribute__((ext_vector_type(8)));
typedef float f32x4 __attribute__((ext_vector_type(4)));
typedef u16 v8u16 __attribute__((ext_vector_type(8)));

#define B_ 32
#define L_ 200
#define D_ 512
#define H_ 8
#define HD_ 64
#define M_ (B_*L_)

__device__ __forceinline__ float bf2f(u16 u) {
  union { float f; unsigned int i; } v; v.i = ((unsigned int)u) << 16; return v.f;
}
__device__ __forceinline__ u16 f2bf(float f) {
  union { float f; unsigned int i; } v; v.f = f;
  unsigned int i = v.i;
  return (u16)((i + 0x7FFFu + ((i >> 16) & 1u)) >> 16);
}
__device__ __forceinline__ bf16x8 as_bf(v8u16 v) { return __builtin_bit_cast(bf16x8, v); }

__device__ __forceinline__ void gload16(const void* g, void* l) {
  __builtin_amdgcn_global_load_lds(
      (const __attribute__((address_space(1))) void*)g,
      (__attribute__((address_space(3))) void*)l,
      16, 0, 0);
}

struct TPtrs { const float* s[12]; };

// ---------------- prep: qb = bf16(x*valid) + fused LN1(layer0) -> Qn  (blocks 0..1599)
//                   + W[k][n] fp32 -> Wt[n][k] bf16 (blocks 1600..2367) ----------------
__global__ __launch_bounds__(256) void prep_kernel(
    const float* __restrict__ x, const unsigned char* __restrict__ mask,
    u16* __restrict__ qb, TPtrs tp, u16* __restrict__ Wt,
    const float* __restrict__ ln1g, const float* __restrict__ ln1b, u16* __restrict__ Qn)
{
  __shared__ float T[64 * 65];
  int bid = blockIdx.x;
  int t = threadIdx.x;
  if (bid < 1600) {
    size_t i = (size_t)bid * 256 + t;
    size_t base = i * 8;
    int tok = (int)(base >> 9);
    float valid = mask[tok] ? 0.f : 1.f;
    float4 v0 = *(const float4*)(x + base);
    float4 v1 = *(const float4*)(x + base + 4);
    v8u16 ob;
    ob[0]=f2bf(v0.x*valid); ob[1]=f2bf(v0.y*valid); ob[2]=f2bf(v0.z*valid); ob[3]=f2bf(v0.w*valid);
    ob[4]=f2bf(v1.x*valid); ob[5]=f2bf(v1.y*valid); ob[6]=f2bf(v1.z*valid); ob[7]=f2bf(v1.w*valid);
    *(v8u16*)(qb + base) = ob;
    int lane = t & 63;
    float xs[8];
    #pragma unroll
    for (int j = 0; j < 8; j++) xs[j] = bf2f(ob[j]);
    float s = 0.f, q = 0.f;
    #pragma unroll
    for (int j = 0; j < 8; j++) { s += xs[j]; q += xs[j] * xs[j]; }
    #pragma unroll
    for (int off = 1; off < 64; off <<= 1) { s += __shfl_xor(s, off); q += __shfl_xor(q, off); }
    float mean = s * (1.f / 512.f);
    float var  = fmaxf(q * (1.f / 512.f) - mean * mean, 0.f);
    float rstd = rsqrtf(var + 1e-8f);
    float4 g0 = *(const float4*)(ln1g + lane * 8);
    float4 g1 = *(const float4*)(ln1g + lane * 8 + 4);
    float4 b0 = *(const float4*)(ln1b + lane * 8);
    float4 b1 = *(const float4*)(ln1b + lane * 8 + 4);
    float gv[8] = {g0.x,g0.y,g0.z,g0.w,g1.x,g1.y,g1.z,g1.w};
    float bv[8] = {b0.x,b0.y,b0.z,b0.w,b1.x,b1.y,b1.z,b1.w};
    v8u16 qn;
    #pragma unroll
    for (int j = 0; j < 8; j++) qn[j] = f2bf((xs[j] - mean) * rstd * gv[j] + bv[j]);
    *(v8u16*)(Qn + base) = qn;
  } else {
    int wb   = bid - 1600;
    int mat  = wb >> 6;
    int tile = wb & 63;
    int tr = tile >> 3, tc = tile & 7;
    const float* src = tp.s[mat];
    #pragma unroll
    for (int i = 0; i < 4; i++) {
      int idx = t + i * 256;
      int row = idx >> 4, c4 = idx & 15;
      float4 v = *(const float4*)(src + (size_t)(tr * 64 + row) * 512 + tc * 64 + c4 * 4);
      T[row * 65 + c4 * 4 + 0] = v.x; T[row * 65 + c4 * 4 + 1] = v.y;
      T[row * 65 + c4 * 4 + 2] = v.z; T[row * 65 + c4 * 4 + 3] = v.w;
    }
    __syncthreads();
    u16* d = Wt + (size_t)mat * 262144;
    #pragma unroll
    for (int i = 0; i < 2; i++) {
      int idx = t + i * 256;
      int row = idx >> 3, c8 = idx & 7;
      v8u16 v;
      #pragma unroll
      for (int j = 0; j < 8; j++) v[j] = f2bf(T[(c8 * 8 + j) * 65 + row]);
      *(v8u16*)(d + (size_t)(tc * 64 + row) * 512 + tr * 64 + c8 * 8) = v;
    }
  }
}

// ---------------- LayerNorm: bf16 in, bf16 or fp32 out, row over D=512 ----------------
template<bool OUTF32>
__global__ __launch_bounds__(256) void ln_kernel(
    const u16* __restrict__ in, const float* __restrict__ g, const float* __restrict__ b,
    u16* __restrict__ outb, float* __restrict__ outf)
{
  int row  = blockIdx.x * 4 + (threadIdx.x >> 6);
  int lane = threadIdx.x & 63;
  size_t base = (size_t)row * 512 + lane * 8;
  v8u16 xv = *(const v8u16*)(in + base);
  float xs[8];
  #pragma unroll
  for (int j = 0; j < 8; j++) xs[j] = bf2f(xv[j]);
  float s = 0.f, q = 0.f;
  #pragma unroll
  for (int j = 0; j < 8; j++) { s += xs[j]; q += xs[j] * xs[j]; }
  #pragma unroll
  for (int off = 1; off < 64; off <<= 1) { s += __shfl_xor(s, off); q += __shfl_xor(q, off); }
  float mean = s * (1.f / 512.f);
  float var  = fmaxf(q * (1.f / 512.f) - mean * mean, 0.f);
  float rstd = rsqrtf(var + 1e-8f);
  float4 g0 = *(const float4*)(g + lane * 8);
  float4 g1 = *(const float4*)(g + lane * 8 + 4);
  float4 b0 = *(const float4*)(b + lane * 8);
  float4 b1 = *(const float4*)(b + lane * 8 + 4);
  float gv[8] = {g0.x,g0.y,g0.z,g0.w,g1.x,g1.y,g1.z,g1.w};
  float bv[8] = {b0.x,b0.y,b0.z,b0.w,b1.x,b1.y,b1.z,b1.w};
  if (OUTF32) {
    float of[8];
    #pragma unroll
    for (int j = 0; j < 8; j++) of[j] = (xs[j] - mean) * rstd * gv[j] + bv[j];
    *(float4*)(outf + base)     = make_float4(of[0], of[1], of[2], of[3]);
    *(float4*)(outf + base + 4) = make_float4(of[4], of[5], of[6], of[7]);
  } else {
    v8u16 ob;
    #pragma unroll
    for (int j = 0; j < 8; j++) ob[j] = f2bf((xs[j] - mean) * rstd * gv[j] + bv[j]);
    *(v8u16*)(outb + base) = ob;
  }
}

// ---------------- BK=128 staging: one 64x128 bf16 tile (16 KB), granule-XOR swizzled ----------------
__device__ __forceinline__ void stage128(const u16* __restrict__ src, int r0, int kk,
                                         u16* dstLds, int wid, int lane) {
  int g = lane & 15;
  #pragma unroll
  for (int j = 0; j < 4; j++) {
    int row = j * 16 + wid * 4 + (lane >> 4);
    int gsrc = (g & 8) | ((g & 7) ^ (row & 7));
    gload16(src + (size_t)(r0 + row) * 512 + kk + gsrc * 8,
            (char*)dstLds + (j * 16 + wid * 4) * 256);
  }
}

// ---------------- single GEMM 128x64, K=512, BK=128 (R15-proven): grid 400 ----------------
template<bool RELU, bool HAS_RES, bool MASK>
__global__ __launch_bounds__(256) void gemm_one(
    const u16* __restrict__ A, const u16* __restrict__ Wt, const float* __restrict__ bias,
    const u16* __restrict__ res, const unsigned char* __restrict__ mask,
    u16* __restrict__ outb)
{
  __shared__ u16 sh[24576];     // 48 KB: As 32 KB | Bs 16 KB
  u16* As = sh;
  u16* Bs = sh + 16384;
  int tile = (blockIdx.x & 7) * 50 + (blockIdx.x >> 3);
  int m0 = (tile >> 3) * 128, n0 = (tile & 7) * 64;
  int tid = threadIdx.x, wid = tid >> 6, lane = tid & 63;
  int l15 = lane & 15, hi = lane >> 4;
  f32x4 acc[2][4] = {};
  for (int s = 0; s < 4; s++) {
    int kk = s * 128;
    stage128(A,  m0,      kk, As,            wid, lane);
    stage128(A,  m0 + 64, kk, As + 64 * 128, wid, lane);
    stage128(Wt, n0,      kk, Bs,            wid, lane);
    __syncthreads();
    #pragma unroll
    for (int ksub = 0; ksub < 4; ksub++) {
      int G = ksub * 4 + hi;
      bf16x8 af[2], bfr[4];
      #pragma unroll
      for (int mi = 0; mi < 2; mi++) {
        int ra = wid * 32 + mi * 16 + l15;
        int lg = (G & 8) | ((G & 7) ^ (ra & 7));
        af[mi] = *(const bf16x8*)(As + ra * 128 + lg * 8);
      }
      #pragma unroll
      for (int ni = 0; ni < 4; ni++) {
        int rn = ni * 16 + l15;
        int lg = (G & 8) | ((G & 7) ^ (rn & 7));
        bfr[ni] = *(const bf16x8*)(Bs + rn * 128 + lg * 8);
      }
      #pragma unroll
      for (int mi = 0; mi < 2; mi++)
        #pragma unroll
        for (int ni = 0; ni < 4; ni++)
          acc[mi][ni] = __builtin_amdgcn_mfma_f32_16x16x32_bf16(af[mi], bfr[ni], acc[mi][ni], 0, 0, 0);
    }
    __syncthreads();
  }
  #pragma unroll
  for (int ni = 0; ni < 4; ni++) {
    int gc = n0 + ni * 16 + l15;
    float bvv = bias[gc];
    #pragma unroll
    for (int mi = 0; mi < 2; mi++) {
      int grb = m0 + wid * 32 + mi * 16 + hi * 4;
      #pragma unroll
      for (int r = 0; r < 4; r++) {
        int gr = grb + r;
        float v = acc[mi][ni][r] + bvv;
        if (HAS_RES) v += bf2f(res[(size_t)gr * 512 + gc]);
        if (RELU) v = fmaxf(v, 0.f);
        if (MASK) v = mask[gr] ? 0.f : v;
        outb[(size_t)gr * 512 + gc] = f2bf(v);
      }
    }
  }
}

// ---------------- merged Q | K+V GEMMs: grid 800, tiles 128x64.
// Tiles 0..399 = Q (A=Qn); 400..799 = K+V per block (one 128-row A-stage feeds both
// B-streams). V written directly in transposed Vt layout.
__global__ __launch_bounds__(256) void gemm_qkv(
    const u16* __restrict__ Aq, const u16* __restrict__ Akv,
    const u16* __restrict__ Wtq, const u16* __restrict__ Wtk, const u16* __restrict__ Wtv,
    const float* __restrict__ bq, const float* __restrict__ bk, const float* __restrict__ bv,
    u16* __restrict__ outq, u16* __restrict__ outk, u16* __restrict__ outvt)
{
  __shared__ u16 sh[32768];    // 64 KB: As 32 KB | B0 16 KB | B1 16 KB
  u16* As = sh;
  u16* B0 = sh + 16384;
  u16* B1 = sh + 24576;
  int bid = blockIdx.x;
  int tile = (bid & 7) * 100 + (bid >> 3);   // bijective over 0..799
  int tid = threadIdx.x, wid = tid >> 6, lane = tid & 63;
  int l15 = lane & 15, hi = lane >> 4;

  if (tile < 400) {
    int m0 = (tile >> 3) * 128, n0 = (tile & 7) * 64;
    f32x4 acc[2][4] = {};
    for (int s = 0; s < 4; s++) {
      int kk = s * 128;
      stage128(Aq,  m0,      kk, As,            wid, lane);
      stage128(Aq,  m0 + 64, kk, As + 64 * 128, wid, lane);
      stage128(Wtq, n0,      kk, B0,            wid, lane);
      __syncthreads();
      #pragma unroll
      for (int ksub = 0; ksub < 4; ksub++) {
        int G = ksub * 4 + hi;
        bf16x8 af[2], bfr[4];
        #pragma unroll
        for (int mi = 0; mi < 2; mi++) {
          int ra = wid * 32 + mi * 16 + l15;
          int lg = (G & 8) | ((G & 7) ^ (ra & 7));
          af[mi] = *(const bf16x8*)(As + ra * 128 + lg * 8);
        }
        #pragma unroll
        for (int ni = 0; ni < 4; ni++) {
          int rn = ni * 16 + l15;
          int lg = (G & 8) | ((G & 7) ^ (rn & 7));
          bfr[ni] = *(const bf16x8*)(B0 + rn * 128 + lg * 8);
        }
        #pragma unroll
        for (int mi = 0; mi < 2; mi++)
          #pragma unroll
          for (int ni = 0; ni < 4; ni++)
            acc[mi][ni] = __builtin_amdgcn_mfma_f32_16x16x32_bf16(af[mi], bfr[ni], acc[mi][ni], 0, 0, 0);
      }
      __syncthreads();
    }
    #pragma unroll
    for (int ni = 0; ni < 4; ni++) {
      int gc = n0 + ni * 16 + l15;
      float bvv = bq[gc];
      #pragma unroll
      for (int mi = 0; mi < 2; mi++) {
        int grb = m0 + wid * 32 + mi * 16 + hi * 4;
        #pragma unroll
        for (int r = 0; r < 4; r++)
          outq[(size_t)(grb + r) * 512 + gc] = f2bf(acc[mi][ni][r] + bvv);
      }
    }
  } else {
    int t2 = tile - 400;
    int m0 = (t2 >> 3) * 128, n0 = (t2 & 7) * 64;
    f32x4 ak[2][4] = {}, av[2][4] = {};
    for (int s = 0; s < 4; s++) {
      int kk = s * 128;
      stage128(Akv, m0,      kk, As,            wid, lane);
      stage128(Akv, m0 + 64, kk, As + 64 * 128, wid, lane);
      stage128(Wtk, n0,      kk, B0,            wid, lane);
      stage128(Wtv, n0,      kk, B1,            wid, lane);
      __syncthreads();
      #pragma unroll
      for (int ksub = 0; ksub < 4; ksub++) {
        int G = ksub * 4 + hi;
        bf16x8 af[2], bkf[4], bvf[4];
        #pragma unroll
        for (int mi = 0; mi < 2; mi++) {
          int ra = wid * 32 + mi * 16 + l15;
          int lg = (G & 8) | ((G & 7) ^ (ra & 7));
          af[mi] = *(const bf16x8*)(As + ra * 128 + lg * 8);
        }
        #pragma unroll
        for (int ni = 0; ni < 4; ni++) {
          int rn = ni * 16 + l15;
          int lg = (G & 8) | ((G & 7) ^ (rn & 7));
          bkf[ni] = *(const bf16x8*)(B0 + rn * 128 + lg * 8);
          bvf[ni] = *(const bf16x8*)(B1 + rn * 128 + lg * 8);
        }
        #pragma unroll
        for (int mi = 0; mi < 2; mi++)
          #pragma unroll
          for (int ni = 0; ni < 4; ni++) {
            ak[mi][ni] = __builtin_amdgcn_mfma_f32_16x16x32_bf16(af[mi], bkf[ni], ak[mi][ni], 0, 0, 0);
            av[mi][ni] = __builtin_amdgcn_mfma_f32_16x16x32_bf16(af[mi], bvf[ni], av[mi][ni], 0, 0, 0);
          }
      }
      __syncthreads();
    }
    #pragma unroll
    for (int ni = 0; ni < 4; ni++) {
      int gc = n0 + ni * 16 + l15;
      float bkv = bk[gc], bvv = bv[gc];
      int h = gc >> 6, hd = gc & 63;
      #pragma unroll
      for (int mi = 0; mi < 2; mi++) {
        int grb = m0 + wid * 32 + mi * 16 + hi * 4;
        #pragma unroll
        for (int r = 0; r < 4; r++) {
          int gr = grb + r;
          outk[(size_t)gr * 512 + gc] = f2bf(ak[mi][ni][r] + bkv);
          int b = gr / 200, l = gr - b * 200;
          outvt[((size_t)(b * 8 + h) * 64 + hd) * 224 + l] = f2bf(av[mi][ni][r] + bvv);
        }
      }
    }
  }
}

// ---------------- attention (R9-proven): 1 wave per WG, no K/V staging, 2 KB LDS P-slot ----------------
__global__ __launch_bounds__(64) void attn_kernel(
    const u16* __restrict__ Qh, const u16* __restrict__ Kh,
    const u16* __restrict__ Vt, u16* __restrict__ ctx)
{
  __shared__ u16 Pb[2][16 * 32];
  int bid = blockIdx.x;
  int xcd = bid & 7, j = bid >> 3;
  int bh_hi = j / 7, s = j - bh_hi * 7;
  int bh = bh_hi * 8 + xcd;
  int b = bh >> 3, h = bh & 7;
  int lane = threadIdx.x;
  int l15 = lane & 15, hi = lane >> 4;

  const u16* Kg = Kh + (size_t)(b * L_) * D_ + h * HD_;
  const u16* Vg = Vt + (size_t)bh * 64 * 224;

  int tA = (s < 6) ? (12 - s) : 6;
  int tB = (s < 6) ? s : -1;

  for (int jj = 0; jj < 2; jj++) {
    int t = jj ? tB : tA;
    if (t < 0) break;
    int q0 = t * 16;
    int qrow = q0 + l15; if (qrow > L_ - 1) qrow = L_ - 1;
    const u16* Qg = Qh + (size_t)(b * L_ + qrow) * D_ + h * HD_ + hi * 8;
    bf16x8 aq0 = as_bf(*(const v8u16*)(Qg));
    bf16x8 aq1 = as_bf(*(const v8u16*)(Qg + 32));

    f32x4 sv[13];
    float m0[4];
    #pragma unroll
    for (int r = 0; r < 4; r++) m0[r] = -3.0e38f;

    #pragma unroll
    for (int kt = 0; kt < 13; kt++) {
      if (kt <= t) {
        const u16* kp = Kg + (size_t)(kt * 16 + l15) * D_ + hi * 8;
        bf16x8 bk0 = as_bf(*(const v8u16*)(kp));
        bf16x8 bk1 = as_bf(*(const v8u16*)(kp + 32));
        f32x4 acq = {0.f, 0.f, 0.f, 0.f};
        acq = __builtin_amdgcn_mfma_f32_16x16x32_bf16(aq0, bk0, acq, 0, 0, 0);
        acq = __builtin_amdgcn_mfma_f32_16x16x32_bf16(aq1, bk1, acq, 0, 0, 0);
        #pragma unroll
        for (int r = 0; r < 4; r++) {
          int qr = q0 + hi * 4 + r;
          int kc = kt * 16 + l15;
          float val = (kc <= qr && qr < L_) ? acq[r] * 0.125f : -3.0e38f;
          sv[kt][r] = val;
          m0[r] = fmaxf(m0[r], val);
        }
      }
    }
    #pragma unroll
    for (int r = 0; r < 4; r++) {
      #pragma unroll
      for (int off = 1; off < 16; off <<= 1)
        m0[r] = fmaxf(m0[r], __shfl_xor(m0[r], off));
      if (m0[r] < -1e37f) m0[r] = 0.f;
    }
    float sum[4] = {0.f, 0.f, 0.f, 0.f};
    #pragma unroll
    for (int kt = 0; kt < 13; kt++) {
      if (kt <= t) {
        #pragma unroll
        for (int r = 0; r < 4; r++) {
          float p = __expf(sv[kt][r] - m0[r]);
          sv[kt][r] = p;
          sum[r] += p;
        }
      }
    }
    #pragma unroll
    for (int r = 0; r < 4; r++) {
      #pragma unroll
      for (int off = 1; off < 16; off <<= 1) sum[r] += __shfl_xor(sum[r], off);
    }
    float inv[4];
    #pragma unroll
    for (int r = 0; r < 4; r++) inv[r] = sum[r] > 0.f ? 1.f / sum[r] : 0.f;

    int ksmax = (t + 2) >> 1;
    f32x4 acc[4] = {};
    #pragma unroll
    for (int ks = 0; ks < 7; ks++) {
      if (ks < ksmax) {
        u16* Ps = (u16*)Pb[ks & 1];
        #pragma unroll
        for (int half = 0; half < 2; half++) {
          int kt = ks * 2 + half;
          #pragma unroll
          for (int r = 0; r < 4; r++) {
            float pv = (kt <= t) ? sv[kt][r] : 0.f;
            Ps[(hi * 4 + r) * 32 + half * 16 + l15] = f2bf(pv);
          }
        }
        bf16x8 ap = as_bf(*(const v8u16*)(Ps + l15 * 32 + hi * 8));
        #pragma unroll
        for (int nt = 0; nt < 4; nt++) {
          bf16x8 bvv = as_bf(*(const v8u16*)(Vg + (nt * 16 + l15) * 224 + ks * 32 + hi * 8));
          acc[nt] = __builtin_amdgcn_mfma_f32_16x16x32_bf16(ap, bvv, acc[nt], 0, 0, 0);
        }
      }
    }
    #pragma unroll
    for (int nt = 0; nt < 4; nt++) {
      #pragma unroll
      for (int r = 0; r < 4; r++) {
        int qr = q0 + hi * 4 + r;
        if (qr < L_) ctx[(size_t)(b * L_ + qr) * D_ + h * HD_ + nt * 16 + l15] = f2bf(acc[nt][r] * inv[r]);
      }
    }
  }
}

// ---------------- host ----------------
extern "C" void kernel_launch(void* const* d_in, const int* in_sizes, int n_in,
                              void* d_out, int out_size, void* d_ws, size_t ws_size,
                              hipStream_t stream)
{
  (void)in_sizes; (void)n_in; (void)out_size; (void)ws_size;
  const float* x    = (const float*)d_in[0];
  const unsigned char* mask = (const unsigned char*)d_in[1];
  const float* ln1g = (const float*)d_in[2];
  const float* ln1b = (const float*)d_in[3];
  const float* Wq   = (const float*)d_in[4];
  const float* bq   = (const float*)d_in[5];
  const float* Wk   = (const float*)d_in[6];
  const float* bk   = (const float*)d_in[7];
  const float* Wv   = (const float*)d_in[8];
  const float* bv   = (const float*)d_in[9];
  const float* Wo   = (const float*)d_in[10];
  const float* bo   = (const float*)d_in[11];
  const float* ln2g = (const float*)d_in[12];
  const float* ln2b = (const float*)d_in[13];
  const float* W1   = (const float*)d_in[14];
  const float* b1   = (const float*)d_in[15];
  const float* W2   = (const float*)d_in[16];
  const float* b2   = (const float*)d_in[17];
  const float* lnfg = (const float*)d_in[18];
  const float* lnfb = (const float*)d_in[19];

  char* ws = (char*)d_ws;
  u16* Wt  = (u16*)(ws);                 //  6,291,456 B
  u16* qb  = (u16*)(ws +  6291456);      //  6,553,600 B  current q (bf16)
  u16* Qn  = (u16*)(ws + 12845056);      //  6,553,600 B  LN output (residual)
  u16* qh  = (u16*)(ws + 19398656);      //  6,553,600 B  qh / h1
  u16* kh  = (u16*)(ws + 25952256);      //  6,553,600 B  kh
  u16* vh  = (u16*)(ws + 32505856);      //  6,553,600 B  ctx
  u16* Vtb = (u16*)(ws + 39059456);      //  7,340,032 B  -> end 46,399,488

  TPtrs tp;
  tp.s[0] = Wq; tp.s[1] = Wq + 262144;
  tp.s[2] = Wk; tp.s[3] = Wk + 262144;
  tp.s[4] = Wv; tp.s[5] = Wv + 262144;
  tp.s[6] = Wo; tp.s[7] = Wo + 262144;
  tp.s[8] = W1; tp.s[9] = W1 + 262144;
  tp.s[10] = W2; tp.s[11] = W2 + 262144;

  prep_kernel<<<dim3(2368), dim3(256), 0, stream>>>(x, mask, qb, tp, Wt, ln1g, ln1b, Qn);

  for (int i = 0; i < 2; i++) {
    const u16* Wtq = Wt + (size_t)(0 + i) * 262144;
    const u16* Wtk = Wt + (size_t)(2 + i) * 262144;
    const u16* Wtv = Wt + (size_t)(4 + i) * 262144;
    const u16* Wto = Wt + (size_t)(6 + i) * 262144;
    const u16* Wt1 = Wt + (size_t)(8 + i) * 262144;
    const u16* Wt2 = Wt + (size_t)(10 + i) * 262144;

    if (i) ln_kernel<false><<<dim3(1600), dim3(256), 0, stream>>>(qb, ln1g + 512, ln1b + 512, Qn, nullptr);
    gemm_qkv<<<dim3(800), dim3(256), 0, stream>>>(Qn, qb, Wtq, Wtk, Wtv,
                                                  bq + i * 512, bk + i * 512, bv + i * 512,
                                                  qh, kh, Vtb);
    attn_kernel<<<dim3(1792), dim3(64), 0, stream>>>(qh, kh, Vtb, vh);   // ctx -> vh
    gemm_one<false,true,false><<<dim3(400), dim3(256), 0, stream>>>(vh, Wto, bo + i * 512, Qn, nullptr, qb);
    ln_kernel<false><<<dim3(1600), dim3(256), 0, stream>>>(qb, ln2g + i * 512, ln2b + i * 512, Qn, nullptr);
    gemm_one<true,false,false><<<dim3(400), dim3(256), 0, stream>>>(Qn, Wt1, b1 + i * 512, nullptr, nullptr, qh);
    gemm_one<false,true,true><<<dim3(400), dim3(256), 0, stream>>>(qh, Wt2, b2 + i * 512, Qn, mask, qb);
  }
  ln_kernel<true><<<dim3(1600), dim3(256), 0, stream>>>(qb, lnfg, lnfb, nullptr, (float*)d_out);
}

// Round 19
// 169.157 us; speedup vs baseline: 1.2120x; 1.0090x over previous
//
#include <hip/hip_runtime.h>

typedef unsigned short u16;
typedef __bf16 bfloat;
typedef bfloat bf16x8 __attribute__((ext_vector_type(8)));
typedef float f32x4 __attribute__((ext_vector_type(4)));
typedef u16 v8u16 __attribute__((ext_vector_type(8)));

#define B_ 32
#define L_ 200
#define D_ 512
#define H_ 8
#define HD_ 64
#define M_ (B_*L_)

__device__ __forceinline__ float bf2f(u16 u) {
  union { float f; unsigned int i; } v; v.i = ((unsigned int)u) << 16; return v.f;
}
__device__ __forceinline__ u16 f2bf(float f) {
  union { float f; unsigned int i; } v; v.f = f;
  unsigned int i = v.i;
  return (u16)((i + 0x7FFFu + ((i >> 16) & 1u)) >> 16);
}
__device__ __forceinline__ bf16x8 as_bf(v8u16 v) { return __builtin_bit_cast(bf16x8, v); }

__device__ __forceinline__ void gload16(const void* g, void* l) {
  __builtin_amdgcn_global_load_lds(
      (const __attribute__((address_space(1))) void*)g,
      (__attribute__((address_space(3))) void*)l,
      16, 0, 0);
}

struct TPtrs { const float* s[12]; };

// ---------------- prep: qb = bf16(x*valid) + fused LN1(layer0) -> Qn  (blocks 0..1599)
//                   + W[k][n] fp32 -> Wt[n][k] bf16 (blocks 1600..2367) ----------------
__global__ __launch_bounds__(256) void prep_kernel(
    const float* __restrict__ x, const unsigned char* __restrict__ mask,
    u16* __restrict__ qb, TPtrs tp, u16* __restrict__ Wt,
    const float* __restrict__ ln1g, const float* __restrict__ ln1b, u16* __restrict__ Qn)
{
  __shared__ float T[64 * 65];
  int bid = blockIdx.x;
  int t = threadIdx.x;
  if (bid < 1600) {
    size_t i = (size_t)bid * 256 + t;
    size_t base = i * 8;
    int tok = (int)(base >> 9);
    float valid = mask[tok] ? 0.f : 1.f;
    float4 v0 = *(const float4*)(x + base);
    float4 v1 = *(const float4*)(x + base + 4);
    v8u16 ob;
    ob[0]=f2bf(v0.x*valid); ob[1]=f2bf(v0.y*valid); ob[2]=f2bf(v0.z*valid); ob[3]=f2bf(v0.w*valid);
    ob[4]=f2bf(v1.x*valid); ob[5]=f2bf(v1.y*valid); ob[6]=f2bf(v1.z*valid); ob[7]=f2bf(v1.w*valid);
    *(v8u16*)(qb + base) = ob;
    int lane = t & 63;
    float xs[8];
    #pragma unroll
    for (int j = 0; j < 8; j++) xs[j] = bf2f(ob[j]);
    float s = 0.f, q = 0.f;
    #pragma unroll
    for (int j = 0; j < 8; j++) { s += xs[j]; q += xs[j] * xs[j]; }
    #pragma unroll
    for (int off = 1; off < 64; off <<= 1) { s += __shfl_xor(s, off); q += __shfl_xor(q, off); }
    float mean = s * (1.f / 512.f);
    float var  = fmaxf(q * (1.f / 512.f) - mean * mean, 0.f);
    float rstd = rsqrtf(var + 1e-8f);
    float4 g0 = *(const float4*)(ln1g + lane * 8);
    float4 g1 = *(const float4*)(ln1g + lane * 8 + 4);
    float4 b0 = *(const float4*)(ln1b + lane * 8);
    float4 b1 = *(const float4*)(ln1b + lane * 8 + 4);
    float gv[8] = {g0.x,g0.y,g0.z,g0.w,g1.x,g1.y,g1.z,g1.w};
    float bv[8] = {b0.x,b0.y,b0.z,b0.w,b1.x,b1.y,b1.z,b1.w};
    v8u16 qn;
    #pragma unroll
    for (int j = 0; j < 8; j++) qn[j] = f2bf((xs[j] - mean) * rstd * gv[j] + bv[j]);
    *(v8u16*)(Qn + base) = qn;
  } else {
    int wb   = bid - 1600;
    int mat  = wb >> 6;
    int tile = wb & 63;
    int tr = tile >> 3, tc = tile & 7;
    const float* src = tp.s[mat];
    #pragma unroll
    for (int i = 0; i < 4; i++) {
      int idx = t + i * 256;
      int row = idx >> 4, c4 = idx & 15;
      float4 v = *(const float4*)(src + (size_t)(tr * 64 + row) * 512 + tc * 64 + c4 * 4);
      T[row * 65 + c4 * 4 + 0] = v.x; T[row * 65 + c4 * 4 + 1] = v.y;
      T[row * 65 + c4 * 4 + 2] = v.z; T[row * 65 + c4 * 4 + 3] = v.w;
    }
    __syncthreads();
    u16* d = Wt + (size_t)mat * 262144;
    #pragma unroll
    for (int i = 0; i < 2; i++) {
      int idx = t + i * 256;
      int row = idx >> 3, c8 = idx & 7;
      v8u16 v;
      #pragma unroll
      for (int j = 0; j < 8; j++) v[j] = f2bf(T[(c8 * 8 + j) * 65 + row]);
      *(v8u16*)(d + (size_t)(tc * 64 + row) * 512 + tr * 64 + c8 * 8) = v;
    }
  }
}

// ---------------- LayerNorm: bf16 in, bf16 or fp32 out, row over D=512 ----------------
template<bool OUTF32>
__global__ __launch_bounds__(256) void ln_kernel(
    const u16* __restrict__ in, const float* __restrict__ g, const float* __restrict__ b,
    u16* __restrict__ outb, float* __restrict__ outf)
{
  int row  = blockIdx.x * 4 + (threadIdx.x >> 6);
  int lane = threadIdx.x & 63;
  size_t base = (size_t)row * 512 + lane * 8;
  v8u16 xv = *(const v8u16*)(in + base);
  float xs[8];
  #pragma unroll
  for (int j = 0; j < 8; j++) xs[j] = bf2f(xv[j]);
  float s = 0.f, q = 0.f;
  #pragma unroll
  for (int j = 0; j < 8; j++) { s += xs[j]; q += xs[j] * xs[j]; }
  #pragma unroll
  for (int off = 1; off < 64; off <<= 1) { s += __shfl_xor(s, off); q += __shfl_xor(q, off); }
  float mean = s * (1.f / 512.f);
  float var  = fmaxf(q * (1.f / 512.f) - mean * mean, 0.f);
  float rstd = rsqrtf(var + 1e-8f);
  float4 g0 = *(const float4*)(g + lane * 8);
  float4 g1 = *(const float4*)(g + lane * 8 + 4);
  float4 b0 = *(const float4*)(b + lane * 8);
  float4 b1 = *(const float4*)(b + lane * 8 + 4);
  float gv[8] = {g0.x,g0.y,g0.z,g0.w,g1.x,g1.y,g1.z,g1.w};
  float bv[8] = {b0.x,b0.y,b0.z,b0.w,b1.x,b1.y,b1.z,b1.w};
  if (OUTF32) {
    float of[8];
    #pragma unroll
    for (int j = 0; j < 8; j++) of[j] = (xs[j] - mean) * rstd * gv[j] + bv[j];
    *(float4*)(outf + base)     = make_float4(of[0], of[1], of[2], of[3]);
    *(float4*)(outf + base + 4) = make_float4(of[4], of[5], of[6], of[7]);
  } else {
    v8u16 ob;
    #pragma unroll
    for (int j = 0; j < 8; j++) ob[j] = f2bf((xs[j] - mean) * rstd * gv[j] + bv[j]);
    *(v8u16*)(outb + base) = ob;
  }
}

// ---------------- BK=128 staging: one 64x128 bf16 tile (16 KB), granule-XOR swizzled ----------------
__device__ __forceinline__ void stage128(const u16* __restrict__ src, int r0, int kk,
                                         u16* dstLds, int wid, int lane) {
  int g = lane & 15;
  #pragma unroll
  for (int j = 0; j < 4; j++) {
    int row = j * 16 + wid * 4 + (lane >> 4);
    int gsrc = (g & 8) | ((g & 7) ^ (row & 7));
    gload16(src + (size_t)(r0 + row) * 512 + kk + gsrc * 8,
            (char*)dstLds + (j * 16 + wid * 4) * 256);
  }
}

// ---------------- single GEMM 128x64, K=512, BK=128 (R15-proven): grid 400 ----------------
template<bool RELU, bool HAS_RES, bool MASK>
__global__ __launch_bounds__(256) void gemm_one(
    const u16* __restrict__ A, const u16* __restrict__ Wt, const float* __restrict__ bias,
    const u16* __restrict__ res, const unsigned char* __restrict__ mask,
    u16* __restrict__ outb)
{
  __shared__ u16 sh[24576];     // 48 KB: As 32 KB | Bs 16 KB
  u16* As = sh;
  u16* Bs = sh + 16384;
  int tile = (blockIdx.x & 7) * 50 + (blockIdx.x >> 3);
  int m0 = (tile >> 3) * 128, n0 = (tile & 7) * 64;
  int tid = threadIdx.x, wid = tid >> 6, lane = tid & 63;
  int l15 = lane & 15, hi = lane >> 4;
  f32x4 acc[2][4] = {};
  for (int s = 0; s < 4; s++) {
    int kk = s * 128;
    stage128(A,  m0,      kk, As,            wid, lane);
    stage128(A,  m0 + 64, kk, As + 64 * 128, wid, lane);
    stage128(Wt, n0,      kk, Bs,            wid, lane);
    __syncthreads();
    #pragma unroll
    for (int ksub = 0; ksub < 4; ksub++) {
      int G = ksub * 4 + hi;
      bf16x8 af[2], bfr[4];
      #pragma unroll
      for (int mi = 0; mi < 2; mi++) {
        int ra = wid * 32 + mi * 16 + l15;
        int lg = (G & 8) | ((G & 7) ^ (ra & 7));
        af[mi] = *(const bf16x8*)(As + ra * 128 + lg * 8);
      }
      #pragma unroll
      for (int ni = 0; ni < 4; ni++) {
        int rn = ni * 16 + l15;
        int lg = (G & 8) | ((G & 7) ^ (rn & 7));
        bfr[ni] = *(const bf16x8*)(Bs + rn * 128 + lg * 8);
      }
      #pragma unroll
      for (int mi = 0; mi < 2; mi++)
        #pragma unroll
        for (int ni = 0; ni < 4; ni++)
          acc[mi][ni] = __builtin_amdgcn_mfma_f32_16x16x32_bf16(af[mi], bfr[ni], acc[mi][ni], 0, 0, 0);
    }
    __syncthreads();
  }
  #pragma unroll
  for (int ni = 0; ni < 4; ni++) {
    int gc = n0 + ni * 16 + l15;
    float bvv = bias[gc];
    #pragma unroll
    for (int mi = 0; mi < 2; mi++) {
      int grb = m0 + wid * 32 + mi * 16 + hi * 4;
      #pragma unroll
      for (int r = 0; r < 4; r++) {
        int gr = grb + r;
        float v = acc[mi][ni][r] + bvv;
        if (HAS_RES) v += bf2f(res[(size_t)gr * 512 + gc]);
        if (RELU) v = fmaxf(v, 0.f);
        if (MASK) v = mask[gr] ? 0.f : v;
        outb[(size_t)gr * 512 + gc] = f2bf(v);
      }
    }
  }
}

// ---------------- merged Q | K+V GEMMs: grid 800, tiles 128x64 (R18-proven) ----------------
__global__ __launch_bounds__(256) void gemm_qkv(
    const u16* __restrict__ Aq, const u16* __restrict__ Akv,
    const u16* __restrict__ Wtq, const u16* __restrict__ Wtk, const u16* __restrict__ Wtv,
    const float* __restrict__ bq, const float* __restrict__ bk, const float* __restrict__ bv,
    u16* __restrict__ outq, u16* __restrict__ outk, u16* __restrict__ outvt)
{
  __shared__ u16 sh[32768];    // 64 KB: As 32 KB | B0 16 KB | B1 16 KB
  u16* As = sh;
  u16* B0 = sh + 16384;
  u16* B1 = sh + 24576;
  int bid = blockIdx.x;
  int tile = (bid & 7) * 100 + (bid >> 3);   // bijective over 0..799
  int tid = threadIdx.x, wid = tid >> 6, lane = tid & 63;
  int l15 = lane & 15, hi = lane >> 4;

  if (tile < 400) {
    int m0 = (tile >> 3) * 128, n0 = (tile & 7) * 64;
    f32x4 acc[2][4] = {};
    for (int s = 0; s < 4; s++) {
      int kk = s * 128;
      stage128(Aq,  m0,      kk, As,            wid, lane);
      stage128(Aq,  m0 + 64, kk, As + 64 * 128, wid, lane);
      stage128(Wtq, n0,      kk, B0,            wid, lane);
      __syncthreads();
      #pragma unroll
      for (int ksub = 0; ksub < 4; ksub++) {
        int G = ksub * 4 + hi;
        bf16x8 af[2], bfr[4];
        #pragma unroll
        for (int mi = 0; mi < 2; mi++) {
          int ra = wid * 32 + mi * 16 + l15;
          int lg = (G & 8) | ((G & 7) ^ (ra & 7));
          af[mi] = *(const bf16x8*)(As + ra * 128 + lg * 8);
        }
        #pragma unroll
        for (int ni = 0; ni < 4; ni++) {
          int rn = ni * 16 + l15;
          int lg = (G & 8) | ((G & 7) ^ (rn & 7));
          bfr[ni] = *(const bf16x8*)(B0 + rn * 128 + lg * 8);
        }
        #pragma unroll
        for (int mi = 0; mi < 2; mi++)
          #pragma unroll
          for (int ni = 0; ni < 4; ni++)
            acc[mi][ni] = __builtin_amdgcn_mfma_f32_16x16x32_bf16(af[mi], bfr[ni], acc[mi][ni], 0, 0, 0);
      }
      __syncthreads();
    }
    #pragma unroll
    for (int ni = 0; ni < 4; ni++) {
      int gc = n0 + ni * 16 + l15;
      float bvv = bq[gc];
      #pragma unroll
      for (int mi = 0; mi < 2; mi++) {
        int grb = m0 + wid * 32 + mi * 16 + hi * 4;
        #pragma unroll
        for (int r = 0; r < 4; r++)
          outq[(size_t)(grb + r) * 512 + gc] = f2bf(acc[mi][ni][r] + bvv);
      }
    }
  } else {
    int t2 = tile - 400;
    int m0 = (t2 >> 3) * 128, n0 = (t2 & 7) * 64;
    f32x4 ak[2][4] = {}, av[2][4] = {};
    for (int s = 0; s < 4; s++) {
      int kk = s * 128;
      stage128(Akv, m0,      kk, As,            wid, lane);
      stage128(Akv, m0 + 64, kk, As + 64 * 128, wid, lane);
      stage128(Wtk, n0,      kk, B0,            wid, lane);
      stage128(Wtv, n0,      kk, B1,            wid, lane);
      __syncthreads();
      #pragma unroll
      for (int ksub = 0; ksub < 4; ksub++) {
        int G = ksub * 4 + hi;
        bf16x8 af[2], bkf[4], bvf[4];
        #pragma unroll
        for (int mi = 0; mi < 2; mi++) {
          int ra = wid * 32 + mi * 16 + l15;
          int lg = (G & 8) | ((G & 7) ^ (ra & 7));
          af[mi] = *(const bf16x8*)(As + ra * 128 + lg * 8);
        }
        #pragma unroll
        for (int ni = 0; ni < 4; ni++) {
          int rn = ni * 16 + l15;
          int lg = (G & 8) | ((G & 7) ^ (rn & 7));
          bkf[ni] = *(const bf16x8*)(B0 + rn * 128 + lg * 8);
          bvf[ni] = *(const bf16x8*)(B1 + rn * 128 + lg * 8);
        }
        #pragma unroll
        for (int mi = 0; mi < 2; mi++)
          #pragma unroll
          for (int ni = 0; ni < 4; ni++) {
            ak[mi][ni] = __builtin_amdgcn_mfma_f32_16x16x32_bf16(af[mi], bkf[ni], ak[mi][ni], 0, 0, 0);
            av[mi][ni] = __builtin_amdgcn_mfma_f32_16x16x32_bf16(af[mi], bvf[ni], av[mi][ni], 0, 0, 0);
          }
      }
      __syncthreads();
    }
    #pragma unroll
    for (int ni = 0; ni < 4; ni++) {
      int gc = n0 + ni * 16 + l15;
      float bkv = bk[gc], bvv = bv[gc];
      int h = gc >> 6, hd = gc & 63;
      #pragma unroll
      for (int mi = 0; mi < 2; mi++) {
        int grb = m0 + wid * 32 + mi * 16 + hi * 4;
        #pragma unroll
        for (int r = 0; r < 4; r++) {
          int gr = grb + r;
          outk[(size_t)gr * 512 + gc] = f2bf(ak[mi][ni][r] + bkv);
          int b = gr / 200, l = gr - b * 200;
          outvt[((size_t)(b * 8 + h) * 64 + hd) * 224 + l] = f2bf(av[mi][ni][r] + bvv);
        }
      }
    }
  }
}

// ---------------- attention: 1 wave per WG, ONE tile per wave (grid 3328 = 256 bh x 13 t).
// No K/V staging, 2 KB LDS P-slot. Same per-tile math as R9 (bit-exact).
__global__ __launch_bounds__(64) void attn_kernel(
    const u16* __restrict__ Qh, const u16* __restrict__ Kh,
    const u16* __restrict__ Vt, u16* __restrict__ ctx)
{
  __shared__ u16 Pb[2][16 * 32];
  int bid = blockIdx.x;
  int xcd = bid & 7, j = bid >> 3;
  int bh_hi = j / 13, t = j - bh_hi * 13;
  int bh = bh_hi * 8 + xcd;
  int b = bh >> 3, h = bh & 7;
  int lane = threadIdx.x;
  int l15 = lane & 15, hi = lane >> 4;

  const u16* Kg = Kh + (size_t)(b * L_) * D_ + h * HD_;
  const u16* Vg = Vt + (size_t)bh * 64 * 224;

  int q0 = t * 16;
  int qrow = q0 + l15; if (qrow > L_ - 1) qrow = L_ - 1;
  const u16* Qg = Qh + (size_t)(b * L_ + qrow) * D_ + h * HD_ + hi * 8;
  bf16x8 aq0 = as_bf(*(const v8u16*)(Qg));
  bf16x8 aq1 = as_bf(*(const v8u16*)(Qg + 32));

  f32x4 sv[13];
  float m0[4];
  #pragma unroll
  for (int r = 0; r < 4; r++) m0[r] = -3.0e38f;

  #pragma unroll
  for (int kt = 0; kt < 13; kt++) {
    if (kt <= t) {
      const u16* kp = Kg + (size_t)(kt * 16 + l15) * D_ + hi * 8;
      bf16x8 bk0 = as_bf(*(const v8u16*)(kp));
      bf16x8 bk1 = as_bf(*(const v8u16*)(kp + 32));
      f32x4 acq = {0.f, 0.f, 0.f, 0.f};
      acq = __builtin_amdgcn_mfma_f32_16x16x32_bf16(aq0, bk0, acq, 0, 0, 0);
      acq = __builtin_amdgcn_mfma_f32_16x16x32_bf16(aq1, bk1, acq, 0, 0, 0);
      #pragma unroll
      for (int r = 0; r < 4; r++) {
        int qr = q0 + hi * 4 + r;
        int kc = kt * 16 + l15;
        float val = (kc <= qr && qr < L_) ? acq[r] * 0.125f : -3.0e38f;
        sv[kt][r] = val;
        m0[r] = fmaxf(m0[r], val);
      }
    }
  }
  #pragma unroll
  for (int r = 0; r < 4; r++) {
    #pragma unroll
    for (int off = 1; off < 16; off <<= 1)
      m0[r] = fmaxf(m0[r], __shfl_xor(m0[r], off));
    if (m0[r] < -1e37f) m0[r] = 0.f;
  }
  float sum[4] = {0.f, 0.f, 0.f, 0.f};
  #pragma unroll
  for (int kt = 0; kt < 13; kt++) {
    if (kt <= t) {
      #pragma unroll
      for (int r = 0; r < 4; r++) {
        float p = __expf(sv[kt][r] - m0[r]);
        sv[kt][r] = p;
        sum[r] += p;
      }
    }
  }
  #pragma unroll
  for (int r = 0; r < 4; r++) {
    #pragma unroll
    for (int off = 1; off < 16; off <<= 1) sum[r] += __shfl_xor(sum[r], off);
  }
  float inv[4];
  #pragma unroll
  for (int r = 0; r < 4; r++) inv[r] = sum[r] > 0.f ? 1.f / sum[r] : 0.f;

  int ksmax = (t + 2) >> 1;
  f32x4 acc[4] = {};
  #pragma unroll
  for (int ks = 0; ks < 7; ks++) {
    if (ks < ksmax) {
      u16* Ps = (u16*)Pb[ks & 1];
      #pragma unroll
      for (int half = 0; half < 2; half++) {
        int kt = ks * 2 + half;
        #pragma unroll
        for (int r = 0; r < 4; r++) {
          float pv = (kt <= t) ? sv[kt][r] : 0.f;
          Ps[(hi * 4 + r) * 32 + half * 16 + l15] = f2bf(pv);
        }
      }
      bf16x8 ap = as_bf(*(const v8u16*)(Ps + l15 * 32 + hi * 8));
      #pragma unroll
      for (int nt = 0; nt < 4; nt++) {
        bf16x8 bvv = as_bf(*(const v8u16*)(Vg + (nt * 16 + l15) * 224 + ks * 32 + hi * 8));
        acc[nt] = __builtin_amdgcn_mfma_f32_16x16x32_bf16(ap, bvv, acc[nt], 0, 0, 0);
      }
    }
  }
  #pragma unroll
  for (int nt = 0; nt < 4; nt++) {
    #pragma unroll
    for (int r = 0; r < 4; r++) {
      int qr = q0 + hi * 4 + r;
      if (qr < L_) ctx[(size_t)(b * L_ + qr) * D_ + h * HD_ + nt * 16 + l15] = f2bf(acc[nt][r] * inv[r]);
    }
  }
}

// ---------------- host ----------------
extern "C" void kernel_launch(void* const* d_in, const int* in_sizes, int n_in,
                              void* d_out, int out_size, void* d_ws, size_t ws_size,
                              hipStream_t stream)
{
  (void)in_sizes; (void)n_in; (void)out_size; (void)ws_size;
  const float* x    = (const float*)d_in[0];
  const unsigned char* mask = (const unsigned char*)d_in[1];
  const float* ln1g = (const float*)d_in[2];
  const float* ln1b = (const float*)d_in[3];
  const float* Wq   = (const float*)d_in[4];
  const float* bq   = (const float*)d_in[5];
  const float* Wk   = (const float*)d_in[6];
  const float* bk   = (const float*)d_in[7];
  const float* Wv   = (const float*)d_in[8];
  const float* bv   = (const float*)d_in[9];
  const float* Wo   = (const float*)d_in[10];
  const float* bo   = (const float*)d_in[11];
  const float* ln2g = (const float*)d_in[12];
  const float* ln2b = (const float*)d_in[13];
  const float* W1   = (const float*)d_in[14];
  const float* b1   = (const float*)d_in[15];
  const float* W2   = (const float*)d_in[16];
  const float* b2   = (const float*)d_in[17];
  const float* lnfg = (const float*)d_in[18];
  const float* lnfb = (const float*)d_in[19];

  char* ws = (char*)d_ws;
  u16* Wt  = (u16*)(ws);                 //  6,291,456 B
  u16* qb  = (u16*)(ws +  6291456);      //  6,553,600 B  current q (bf16)
  u16* Qn  = (u16*)(ws + 12845056);      //  6,553,600 B  LN output (residual)
  u16* qh  = (u16*)(ws + 19398656);      //  6,553,600 B  qh / h1
  u16* kh  = (u16*)(ws + 25952256);      //  6,553,600 B  kh
  u16* vh  = (u16*)(ws + 32505856);      //  6,553,600 B  ctx
  u16* Vtb = (u16*)(ws + 39059456);      //  7,340,032 B  -> end 46,399,488

  TPtrs tp;
  tp.s[0] = Wq; tp.s[1] = Wq + 262144;
  tp.s[2] = Wk; tp.s[3] = Wk + 262144;
  tp.s[4] = Wv; tp.s[5] = Wv + 262144;
  tp.s[6] = Wo; tp.s[7] = Wo + 262144;
  tp.s[8] = W1; tp.s[9] = W1 + 262144;
  tp.s[10] = W2; tp.s[11] = W2 + 262144;

  prep_kernel<<<dim3(2368), dim3(256), 0, stream>>>(x, mask, qb, tp, Wt, ln1g, ln1b, Qn);

  for (int i = 0; i < 2; i++) {
    const u16* Wtq = Wt + (size_t)(0 + i) * 262144;
    const u16* Wtk = Wt + (size_t)(2 + i) * 262144;
    const u16* Wtv = Wt + (size_t)(4 + i) * 262144;
    const u16* Wto = Wt + (size_t)(6 + i) * 262144;
    const u16* Wt1 = Wt + (size_t)(8 + i) * 262144;
    const u16* Wt2 = Wt + (size_t)(10 + i) * 262144;

    if (i) ln_kernel<false><<<dim3(1600), dim3(256), 0, stream>>>(qb, ln1g + 512, ln1b + 512, Qn, nullptr);
    gemm_qkv<<<dim3(800), dim3(256), 0, stream>>>(Qn, qb, Wtq, Wtk, Wtv,
                                                  bq + i * 512, bk + i * 512, bv + i * 512,
                                                  qh, kh, Vtb);
    attn_kernel<<<dim3(3328), dim3(64), 0, stream>>>(qh, kh, Vtb, vh);   // ctx -> vh
    gemm_one<false,true,false><<<dim3(400), dim3(256), 0, stream>>>(vh, Wto, bo + i * 512, Qn, nullptr, qb);
    ln_kernel<false><<<dim3(1600), dim3(256), 0, stream>>>(qb, ln2g + i * 512, ln2b + i * 512, Qn, nullptr);
    gemm_one<true,false,false><<<dim3(400), dim3(256), 0, stream>>>(Qn, Wt1, b1 + i * 512, nullptr, nullptr, qh);
    gemm_one<false,true,true><<<dim3(400), dim3(256), 0, stream>>>(qh, Wt2, b2 + i * 512, Qn, mask, qb);
  }
  ln_kernel<true><<<dim3(1600), dim3(256), 0, stream>>>(qb, lnfg, lnfb, nullptr, (float*)d_out);
}